// Round 3
// baseline (364.018 us; speedup 1.0000x reference)
//
#include <hip/hip_runtime.h>
#include <cstddef>

#define B_ 8
#define N_ 1024
#define C_ 512
#define H_ 8
#define DH_ 64
#define QKVLD 1536
#define SCALE_ 0.125f
#define NEG_ -1.0e9f

typedef _Float16 f16;
typedef f16  f16x4 __attribute__((ext_vector_type(4)));
typedef f16  f16x8 __attribute__((ext_vector_type(8)));
typedef float f32x4 __attribute__((ext_vector_type(4)));

static __device__ __forceinline__ f16x4 cvt4(float4 v) {
    f16x4 r; r[0] = (f16)v.x; r[1] = (f16)v.y; r[2] = (f16)v.z; r[3] = (f16)v.w;
    return r;
}

// ---------------------------------------------------------------------------
// f16-MFMA GEMM (used for QKV only): C[M,Nn] = A[M,K] * Bt[Nn,K]^T + bias
// ---------------------------------------------------------------------------
template<int BN, bool BHALF>
__device__ __forceinline__ void gemm_core(
    const float* __restrict__ A, int lda,
    const void* __restrict__ Bv, int ldb,
    const float* __restrict__ bias, float scale,
    float* __restrict__ Cc, int ldc, int K, int bm, int bn)
{
    constexpr int FJ = BN / 32;
    __shared__ __align__(16) f16 Af[128][40];
    __shared__ __align__(16) f16 Bf[BN][40];
    const int tid  = threadIdx.x;
    const int wid  = tid >> 6, lane = tid & 63;
    const int wm   = (wid >> 1) * 64, wn = (wid & 1) * (BN / 2);
    const int lrow = lane & 15, kg = lane >> 4;
    const int ar = tid >> 3, ac = (tid & 7) << 2;

    f32x4 acc[4][FJ];
#pragma unroll
    for (int i = 0; i < 4; ++i)
#pragma unroll
        for (int j = 0; j < FJ; ++j) acc[i][j] = (f32x4){0.f, 0.f, 0.f, 0.f};

    for (int k0 = 0; k0 < K; k0 += 32) {
        float4 a0 = *(const float4*)(A + (size_t)(bm + ar     ) * lda + k0 + ac);
        float4 a1 = *(const float4*)(A + (size_t)(bm + ar + 32) * lda + k0 + ac);
        float4 a2 = *(const float4*)(A + (size_t)(bm + ar + 64) * lda + k0 + ac);
        float4 a3 = *(const float4*)(A + (size_t)(bm + ar + 96) * lda + k0 + ac);
        const float* Bp = (const float*)Bv;
        float4 b0 = *(const float4*)(Bp + (size_t)(bn + ar     ) * ldb + k0 + ac);
        float4 b1 = *(const float4*)(Bp + (size_t)(bn + ar + 32) * ldb + k0 + ac);
        float4 b2 = *(const float4*)(Bp + (size_t)(bn + ar + 64) * ldb + k0 + ac);
        float4 b3 = *(const float4*)(Bp + (size_t)(bn + ar + 96) * ldb + k0 + ac);
        __syncthreads();
        *(f16x4*)&Af[ar     ][ac] = cvt4(a0);
        *(f16x4*)&Af[ar + 32][ac] = cvt4(a1);
        *(f16x4*)&Af[ar + 64][ac] = cvt4(a2);
        *(f16x4*)&Af[ar + 96][ac] = cvt4(a3);
        *(f16x4*)&Bf[ar     ][ac] = cvt4(b0);
        *(f16x4*)&Bf[ar + 32][ac] = cvt4(b1);
        *(f16x4*)&Bf[ar + 64][ac] = cvt4(b2);
        *(f16x4*)&Bf[ar + 96][ac] = cvt4(b3);
        __syncthreads();
        f16x8 af[4], bfv[FJ];
#pragma unroll
        for (int i = 0; i < 4; ++i)
            af[i] = *(const f16x8*)&Af[wm + i * 16 + lrow][kg * 8];
#pragma unroll
        for (int j = 0; j < FJ; ++j)
            bfv[j] = *(const f16x8*)&Bf[wn + j * 16 + lrow][kg * 8];
#pragma unroll
        for (int i = 0; i < 4; ++i)
#pragma unroll
            for (int j = 0; j < FJ; ++j)
                acc[i][j] = __builtin_amdgcn_mfma_f32_16x16x32_f16(af[i], bfv[j], acc[i][j], 0, 0, 0);
    }
#pragma unroll
    for (int j = 0; j < FJ; ++j) {
        const int col = bn + wn + j * 16 + lrow;
        const float bv = bias ? bias[col] : 0.f;
#pragma unroll
        for (int i = 0; i < 4; ++i) {
            const int row0 = bm + wm + i * 16 + kg * 4;
#pragma unroll
            for (int r = 0; r < 4; ++r)
                Cc[(size_t)(row0 + r) * ldc + col] = acc[i][j][r] * scale + bv;
        }
    }
}

__global__ __launch_bounds__(256) void k_qkv(const float* __restrict__ x,
                                             const float* __restrict__ w,
                                             const float* __restrict__ b,
                                             float* __restrict__ o) {
    gemm_core<128, false>(x, C_, w, C_, b, 1.f, o, QKVLD, C_,
                          blockIdx.y * 128, blockIdx.x * 128);
}

// ---------------------------------------------------------------------------
// packs: K -> f16 [b][m][512]; proj_w -> f16 [co][ci]; V -> f16 [b*8+h][d][m]
// ---------------------------------------------------------------------------
__global__ __launch_bounds__(256) void pack_kf(const float* __restrict__ qkv,
                                               f16* __restrict__ kf) {
    const size_t i8 = ((size_t)blockIdx.x * 256 + threadIdx.x) << 3;
    const size_t row = i8 >> 9;
    const int c = (int)(i8 & 511);
    const float* src = qkv + row * QKVLD + C_ + c;
    float4 v0 = *(const float4*)src;
    float4 v1 = *(const float4*)(src + 4);
    f16x8 o;
    o[0]=(f16)v0.x; o[1]=(f16)v0.y; o[2]=(f16)v0.z; o[3]=(f16)v0.w;
    o[4]=(f16)v1.x; o[5]=(f16)v1.y; o[6]=(f16)v1.z; o[7]=(f16)v1.w;
    *(f16x8*)(kf + i8) = o;
}

__global__ __launch_bounds__(256) void pack_pw(const float* __restrict__ w,
                                               f16* __restrict__ wf) {
    const size_t i8 = ((size_t)blockIdx.x * 256 + threadIdx.x) << 3;
    const float* src = w + i8;
    float4 v0 = *(const float4*)src;
    float4 v1 = *(const float4*)(src + 4);
    f16x8 o;
    o[0]=(f16)v0.x; o[1]=(f16)v0.y; o[2]=(f16)v0.z; o[3]=(f16)v0.w;
    o[4]=(f16)v1.x; o[5]=(f16)v1.y; o[6]=(f16)v1.z; o[7]=(f16)v1.w;
    *(f16x8*)(wf + i8) = o;
}

__global__ __launch_bounds__(256) void pack_vt(const float* __restrict__ qkv,
                                               f16* __restrict__ vt) {
    const int z = blockIdx.x, b = z >> 3, h = z & 7;
    const float* V = qkv + (size_t)b * N_ * QKVLD + 2 * C_ + h * DH_;
    f16* O = vt + (size_t)z * DH_ * N_;
    __shared__ __align__(16) f16 T[64][72];
    const int t = threadIdx.x;
    for (int m0 = 0; m0 < N_; m0 += 64) {
#pragma unroll
        for (int it = 0; it < 4; ++it) {
            const int m = (t >> 4) + it * 16, d = (t & 15) * 4;
            float4 v = *(const float4*)(V + (size_t)(m0 + m) * QKVLD + d);
            T[d + 0][m] = (f16)v.x; T[d + 1][m] = (f16)v.y;
            T[d + 2][m] = (f16)v.z; T[d + 3][m] = (f16)v.w;
        }
        __syncthreads();
#pragma unroll
        for (int it = 0; it < 2; ++it) {
            const int d = (t >> 3) + it * 32, m = (t & 7) << 3;
            *(f16x8*)(O + (size_t)d * N_ + m0 + m) = *(const f16x8*)&T[d][m];
        }
        __syncthreads();
    }
}

// ---------------------------------------------------------------------------
// Fused: premix+softmax+postmix (flash 2-pass) + attn2 write + PV + proj.
// Block = (qtile of 32 rows, b). 4 waves: phase grid 2q x 2m; PV: 2 g's/wave.
// ---------------------------------------------------------------------------
__global__ __launch_bounds__(256, 2) void fused_attn(
    const float* __restrict__ qkv,
    const f16*  __restrict__ kf,
    const f16*  __restrict__ vt,
    const f16*  __restrict__ pwf,
    const float* __restrict__ mask,
    const float* __restrict__ pl_w, const float* __restrict__ pl_b,
    const float* __restrict__ pw_w, const float* __restrict__ pw_b,
    const float* __restrict__ proj_b,
    float* __restrict__ attn,
    float* __restrict__ out)
{
    __shared__ __align__(16) f16 Qs[32][520];     // Q (f16, scaled); later o1 tile
    __shared__ __align__(16) f16 Ps[8][32][40];   // attn2 f16 tile for PV
    __shared__ float Stat[2][2][8][2][16];        // [wq][wm][g][M/S][q&15]

    const int qt = blockIdx.x, b = blockIdx.y;
    const int q0 = qt * 32;
    const int tid = threadIdx.x;
    const int w = tid >> 6, l = tid & 63;
    const int wq = w >> 1, wm = w & 1;
    const int qh = wq << 4, mh = wm << 4;
    const int lc = l & 15, lr4 = l >> 4;

    // stage Q tile -> f16 (SCALE folded in; exact pow2 scaling)
    {
        const int qrow = tid >> 3, c0 = (tid & 7) << 6;
        const float* src = qkv + (size_t)(b * N_ + q0 + qrow) * QKVLD + c0;
#pragma unroll
        for (int c = 0; c < 64; c += 4) {
            float4 v = *(const float4*)(src + c);
            f16x4 o;
            o[0]=(f16)(v.x*SCALE_); o[1]=(f16)(v.y*SCALE_);
            o[2]=(f16)(v.z*SCALE_); o[3]=(f16)(v.w*SCALE_);
            *(f16x4*)&Qs[qrow][c0 + c] = o;
        }
    }
    __syncthreads();

    const f16* kfb = kf + (size_t)b * N_ * C_;
    const float* maskb = mask + b * N_;

    float mx[8], sm[8];
#pragma unroll
    for (int g = 0; g < 8; ++g) { mx[g] = -3.0e38f; sm[g] = 0.f; }

    // -------- phase 1: online max/sum of premixed logits --------
    for (int mt = 0; mt < N_; mt += 32) {
        float4 mk4 = *(const float4*)(maskb + mt + mh + (lr4 << 2));
        float mkv[4] = {(1.f-mk4.x)*NEG_, (1.f-mk4.y)*NEG_,
                        (1.f-mk4.z)*NEG_, (1.f-mk4.w)*NEG_};
        float a[8][4];
#pragma unroll
        for (int g = 0; g < 8; ++g) {
            const float bb = pl_b[g];
#pragma unroll
            for (int r = 0; r < 4; ++r) a[g][r] = bb + mkv[r];
        }
#pragma unroll
        for (int h = 0; h < 8; ++h) {
            f32x4 s = (f32x4){0.f, 0.f, 0.f, 0.f};
#pragma unroll
            for (int kk = 0; kk < 2; ++kk) {
                const int c = (h << 6) + (kk << 5) + (lr4 << 3);
                f16x8 af = *(const f16x8*)(kfb + (size_t)(mt + mh + lc) * C_ + c);
                f16x8 bf = *(const f16x8*)&Qs[qh + lc][c];
                s = __builtin_amdgcn_mfma_f32_16x16x32_f16(af, bf, s, 0, 0, 0);
            }
#pragma unroll
            for (int g = 0; g < 8; ++g) {
                const float wv = pl_w[(g << 3) + h];
#pragma unroll
                for (int r = 0; r < 4; ++r) a[g][r] = fmaf(wv, s[r], a[g][r]);
            }
        }
#pragma unroll
        for (int g = 0; g < 8; ++g) {
            float pm = fmaxf(fmaxf(a[g][0], a[g][1]), fmaxf(a[g][2], a[g][3]));
            float nm = fmaxf(mx[g], pm);
            float t  = sm[g] * __expf(mx[g] - nm);
#pragma unroll
            for (int r = 0; r < 4; ++r) t += __expf(a[g][r] - nm);
            sm[g] = t; mx[g] = nm;
        }
    }
    // combine: in-wave across m-subgroups (lanes xor 16, 32)
#pragma unroll
    for (int g = 0; g < 8; ++g) {
#pragma unroll
        for (int off = 16; off < 64; off <<= 1) {
            float m2 = __shfl_xor(mx[g], off);
            float s2 = __shfl_xor(sm[g], off);
            float nm = fmaxf(mx[g], m2);
            sm[g] = sm[g] * __expf(mx[g] - nm) + s2 * __expf(m2 - nm);
            mx[g] = nm;
        }
    }
    if (l < 16) {
#pragma unroll
        for (int g = 0; g < 8; ++g) {
            Stat[wq][wm][g][0][l] = mx[g];
            Stat[wq][wm][g][1][l] = sm[g];
        }
    }
    __syncthreads();
    float invs[8];
#pragma unroll
    for (int g = 0; g < 8; ++g) {
        float m2 = Stat[wq][wm ^ 1][g][0][lc];
        float s2 = Stat[wq][wm ^ 1][g][1][lc];
        float nm = fmaxf(mx[g], m2);
        sm[g] = sm[g] * __expf(mx[g] - nm) + s2 * __expf(m2 - nm);
        mx[g] = nm;
        invs[g] = 1.f / sm[g];
    }

    // -------- phase 2: recompute, normalize, postmix, write attn2, PV --------
    float* attnb = attn + (size_t)(b * H_) * N_ * N_;
    f32x4 O[2][2][4];   // [g-pair][qf][df]
#pragma unroll
    for (int gp = 0; gp < 2; ++gp)
#pragma unroll
        for (int qf = 0; qf < 2; ++qf)
#pragma unroll
            for (int df = 0; df < 4; ++df) O[gp][qf][df] = (f32x4){0.f,0.f,0.f,0.f};
    const int gg0 = w << 1;

    for (int mt = 0; mt < N_; mt += 32) {
        float4 mk4 = *(const float4*)(maskb + mt + mh + (lr4 << 2));
        float mkv[4] = {(1.f-mk4.x)*NEG_, (1.f-mk4.y)*NEG_,
                        (1.f-mk4.z)*NEG_, (1.f-mk4.w)*NEG_};
        float a[8][4];
#pragma unroll
        for (int g = 0; g < 8; ++g) {
            const float bb = pl_b[g];
#pragma unroll
            for (int r = 0; r < 4; ++r) a[g][r] = bb + mkv[r];
        }
#pragma unroll
        for (int h = 0; h < 8; ++h) {
            f32x4 s = (f32x4){0.f, 0.f, 0.f, 0.f};
#pragma unroll
            for (int kk = 0; kk < 2; ++kk) {
                const int c = (h << 6) + (kk << 5) + (lr4 << 3);
                f16x8 af = *(const f16x8*)(kfb + (size_t)(mt + mh + lc) * C_ + c);
                f16x8 bf = *(const f16x8*)&Qs[qh + lc][c];
                s = __builtin_amdgcn_mfma_f32_16x16x32_f16(af, bf, s, 0, 0, 0);
            }
#pragma unroll
            for (int g = 0; g < 8; ++g) {
                const float wv = pl_w[(g << 3) + h];
#pragma unroll
                for (int r = 0; r < 4; ++r) a[g][r] = fmaf(wv, s[r], a[g][r]);
            }
        }
        float p[8][4];
#pragma unroll
        for (int g = 0; g < 8; ++g)
#pragma unroll
            for (int r = 0; r < 4; ++r)
                p[g][r] = __expf(a[g][r] - mx[g]) * invs[g];

        const int qg = q0 + qh + lc;
        const int mg = mt + mh + (lr4 << 2);
#pragma unroll
        for (int gg = 0; gg < 8; ++gg) {
            const float bb = pw_b[gg];
            float o0 = bb, o1 = bb, o2 = bb, o3 = bb;
#pragma unroll
            for (int g = 0; g < 8; ++g) {
                const float wv = pw_w[(gg << 3) + g];
                o0 = fmaf(wv, p[g][0], o0);
                o1 = fmaf(wv, p[g][1], o1);
                o2 = fmaf(wv, p[g][2], o2);
                o3 = fmaf(wv, p[g][3], o3);
            }
            *(float4*)(attnb + ((size_t)gg * N_ + qg) * N_ + mg) =
                make_float4(o0, o1, o2, o3);
            f16x4 ph; ph[0]=(f16)o0; ph[1]=(f16)o1; ph[2]=(f16)o2; ph[3]=(f16)o3;
            *(f16x4*)&Ps[gg][qh + lc][mh + (lr4 << 2)] = ph;
        }
        __syncthreads();
        // PV: wave handles gg0, gg0+1 over full 32 q
#pragma unroll
        for (int gp = 0; gp < 2; ++gp) {
            const int gg = gg0 + gp;
            const f16* vg = vt + ((size_t)(b * H_ + gg)) * DH_ * N_ + mt + (lr4 << 3);
            f16x8 afr[4];
#pragma unroll
            for (int df = 0; df < 4; ++df)
                afr[df] = *(const f16x8*)(vg + (size_t)((df << 4) + lc) * N_);
#pragma unroll
            for (int qf = 0; qf < 2; ++qf) {
                f16x8 bfr = *(const f16x8*)&Ps[gg][(qf << 4) + lc][lr4 << 3];
#pragma unroll
                for (int df = 0; df < 4; ++df)
                    O[gp][qf][df] = __builtin_amdgcn_mfma_f32_16x16x32_f16(
                        afr[df], bfr, O[gp][qf][df], 0, 0, 0);
            }
        }
        __syncthreads();
    }

    // -------- epilogue: o1 tile -> Qs (f16), fused proj GEMM --------
#pragma unroll
    for (int gp = 0; gp < 2; ++gp)
#pragma unroll
        for (int qf = 0; qf < 2; ++qf)
#pragma unroll
            for (int df = 0; df < 4; ++df) {
                f16x4 ph;
                ph[0]=(f16)O[gp][qf][df][0]; ph[1]=(f16)O[gp][qf][df][1];
                ph[2]=(f16)O[gp][qf][df][2]; ph[3]=(f16)O[gp][qf][df][3];
                *(f16x4*)&Qs[(qf << 4) + lc][((gg0 + gp) << 6) + (df << 4) + (lr4 << 2)] = ph;
            }
    __syncthreads();

    {
        f32x4 acc[8][2];
#pragma unroll
        for (int cof = 0; cof < 8; ++cof)
#pragma unroll
            for (int qf = 0; qf < 2; ++qf) acc[cof][qf] = (f32x4){0.f,0.f,0.f,0.f};
        const int co_w = w << 7;
        for (int ci = 0; ci < C_; ci += 32) {
            f16x8 bfr[2];
#pragma unroll
            for (int qf = 0; qf < 2; ++qf)
                bfr[qf] = *(const f16x8*)&Qs[(qf << 4) + lc][ci + (lr4 << 3)];
#pragma unroll
            for (int cof = 0; cof < 8; ++cof) {
                f16x8 afr = *(const f16x8*)(pwf + (size_t)(co_w + (cof << 4) + lc) * C_ + ci + (lr4 << 3));
#pragma unroll
                for (int qf = 0; qf < 2; ++qf)
                    acc[cof][qf] = __builtin_amdgcn_mfma_f32_16x16x32_f16(
                        afr, bfr[qf], acc[cof][qf], 0, 0, 0);
            }
        }
        float* outb = out + (size_t)(b * N_ + q0) * C_;
#pragma unroll
        for (int cof = 0; cof < 8; ++cof) {
            const int co = co_w + (cof << 4) + (lr4 << 2);
            float4 bias4 = *(const float4*)(proj_b + co);
#pragma unroll
            for (int qf = 0; qf < 2; ++qf) {
                float4 r;
                r.x = acc[cof][qf][0] + bias4.x;
                r.y = acc[cof][qf][1] + bias4.y;
                r.z = acc[cof][qf][2] + bias4.z;
                r.w = acc[cof][qf][3] + bias4.w;
                *(float4*)(outb + (size_t)((qf << 4) + lc) * C_ + co) = r;
            }
        }
    }
}

extern "C" void kernel_launch(void* const* d_in, const int* in_sizes, int n_in,
                              void* d_out, int out_size, void* d_ws, size_t ws_size,
                              hipStream_t stream)
{
    const float* x      = (const float*)d_in[0];
    const float* mask   = (const float*)d_in[1];
    const float* qkv_w  = (const float*)d_in[2];
    const float* qkv_b  = (const float*)d_in[3];
    const float* proj_w = (const float*)d_in[4];
    const float* proj_b = (const float*)d_in[5];
    const float* pl_w   = (const float*)d_in[6];
    const float* pl_b   = (const float*)d_in[7];
    const float* pw_w   = (const float*)d_in[8];
    const float* pw_b   = (const float*)d_in[9];

    float* out  = (float*)d_out;                        // [B,N,C]
    float* attn = out + (size_t)B_ * N_ * C_;           // [B,H,N,N]
    float* qkvb = (float*)d_ws;                         // 50.3 MB
    f16*   kf   = (f16*)(qkvb + (size_t)B_ * N_ * 3 * C_);  // 8.4 MB
    f16*   vt   = kf + (size_t)B_ * N_ * C_;                // 8.4 MB
    f16*   pwf  = vt + (size_t)B_ * N_ * C_;                // 0.5 MB
    (void)in_sizes; (void)n_in; (void)out_size; (void)ws_size;

    // 1) qkv = x @ qkv_w^T + qkv_b
    k_qkv<<<dim3(QKVLD / 128, B_ * N_ / 128), 256, 0, stream>>>(x, qkv_w, qkv_b, qkvb);

    // 2) packs
    pack_kf<<<dim3(2048), 256, 0, stream>>>(qkvb, kf);
    pack_vt<<<dim3(B_ * H_), 256, 0, stream>>>(qkvb, vt);
    pack_pw<<<dim3(128), 256, 0, stream>>>(proj_w, pwf);

    // 3) fused premix+softmax+postmix+attn-write+PV+proj
    fused_attn<<<dim3(N_ / 32, B_), 256, 0, stream>>>(
        qkvb, kf, vt, pwf, mask, pl_w, pl_b, pw_w, pw_b, proj_b, attn, out);
}

// Round 4
// 331.885 us; speedup vs baseline: 1.0968x; 1.0968x over previous
//
#include <hip/hip_runtime.h>
#include <cstddef>

#define B_ 8
#define N_ 1024
#define C_ 512
#define H_ 8
#define DH_ 64
#define QKVLD 1536
#define SCALE_ 0.125f
#define NEG_ -1.0e9f

typedef _Float16 f16;
typedef f16  f16x4 __attribute__((ext_vector_type(4)));
typedef f16  f16x8 __attribute__((ext_vector_type(8)));
typedef float f32x4 __attribute__((ext_vector_type(4)));

static __device__ __forceinline__ f16x4 cvt4(float4 v) {
    f16x4 r; r[0] = (f16)v.x; r[1] = (f16)v.y; r[2] = (f16)v.z; r[3] = (f16)v.w;
    return r;
}

// ---------------------------------------------------------------------------
// f16-MFMA GEMM for QKV: C[M,Nn] = A[M,K] * Bt[Nn,K]^T + bias
// ---------------------------------------------------------------------------
__global__ __launch_bounds__(256) void k_qkv(const float* __restrict__ A,
                                             const float* __restrict__ Bt,
                                             const float* __restrict__ bias,
                                             float* __restrict__ Cc) {
    const int lda = C_, ldb = C_, ldc = QKVLD, K = C_;
    const int bm = blockIdx.y * 128, bn = blockIdx.x * 128;
    __shared__ __align__(16) f16 Af[128][40];
    __shared__ __align__(16) f16 Bf[128][40];
    const int tid  = threadIdx.x;
    const int wid  = tid >> 6, lane = tid & 63;
    const int wm   = (wid >> 1) * 64, wn = (wid & 1) * 64;
    const int lrow = lane & 15, kg = lane >> 4;
    const int ar = tid >> 3, ac = (tid & 7) << 2;

    f32x4 acc[4][4];
#pragma unroll
    for (int i = 0; i < 4; ++i)
#pragma unroll
        for (int j = 0; j < 4; ++j) acc[i][j] = (f32x4){0.f, 0.f, 0.f, 0.f};

    for (int k0 = 0; k0 < K; k0 += 32) {
        float4 a0 = *(const float4*)(A  + (size_t)(bm + ar     ) * lda + k0 + ac);
        float4 a1 = *(const float4*)(A  + (size_t)(bm + ar + 32) * lda + k0 + ac);
        float4 a2 = *(const float4*)(A  + (size_t)(bm + ar + 64) * lda + k0 + ac);
        float4 a3 = *(const float4*)(A  + (size_t)(bm + ar + 96) * lda + k0 + ac);
        float4 b0 = *(const float4*)(Bt + (size_t)(bn + ar     ) * ldb + k0 + ac);
        float4 b1 = *(const float4*)(Bt + (size_t)(bn + ar + 32) * ldb + k0 + ac);
        float4 b2 = *(const float4*)(Bt + (size_t)(bn + ar + 64) * ldb + k0 + ac);
        float4 b3 = *(const float4*)(Bt + (size_t)(bn + ar + 96) * ldb + k0 + ac);
        __syncthreads();
        *(f16x4*)&Af[ar     ][ac] = cvt4(a0);
        *(f16x4*)&Af[ar + 32][ac] = cvt4(a1);
        *(f16x4*)&Af[ar + 64][ac] = cvt4(a2);
        *(f16x4*)&Af[ar + 96][ac] = cvt4(a3);
        *(f16x4*)&Bf[ar     ][ac] = cvt4(b0);
        *(f16x4*)&Bf[ar + 32][ac] = cvt4(b1);
        *(f16x4*)&Bf[ar + 64][ac] = cvt4(b2);
        *(f16x4*)&Bf[ar + 96][ac] = cvt4(b3);
        __syncthreads();
        f16x8 af[4], bfv[4];
#pragma unroll
        for (int i = 0; i < 4; ++i)
            af[i] = *(const f16x8*)&Af[wm + i * 16 + lrow][kg * 8];
#pragma unroll
        for (int j = 0; j < 4; ++j)
            bfv[j] = *(const f16x8*)&Bf[wn + j * 16 + lrow][kg * 8];
#pragma unroll
        for (int i = 0; i < 4; ++i)
#pragma unroll
            for (int j = 0; j < 4; ++j)
                acc[i][j] = __builtin_amdgcn_mfma_f32_16x16x32_f16(af[i], bfv[j], acc[i][j], 0, 0, 0);
    }
#pragma unroll
    for (int j = 0; j < 4; ++j) {
        const int col = bn + wn + j * 16 + lrow;
        const float bv = bias[col];
#pragma unroll
        for (int i = 0; i < 4; ++i) {
            const int row0 = bm + wm + i * 16 + kg * 4;
#pragma unroll
            for (int r = 0; r < 4; ++r)
                Cc[(size_t)(row0 + r) * ldc + col] = acc[i][j][r] + bv;
        }
    }
}

// ---------------------------------------------------------------------------
// packs: K -> f16 [b][m][512]; proj_w -> f16 [co][ci]; V -> f16 [b*8+h][d][m]
// ---------------------------------------------------------------------------
__global__ __launch_bounds__(256) void pack_kf(const float* __restrict__ qkv,
                                               f16* __restrict__ kf) {
    const size_t i8 = ((size_t)blockIdx.x * 256 + threadIdx.x) << 3;
    const size_t row = i8 >> 9;
    const int c = (int)(i8 & 511);
    const float* src = qkv + row * QKVLD + C_ + c;
    float4 v0 = *(const float4*)src;
    float4 v1 = *(const float4*)(src + 4);
    f16x8 o;
    o[0]=(f16)v0.x; o[1]=(f16)v0.y; o[2]=(f16)v0.z; o[3]=(f16)v0.w;
    o[4]=(f16)v1.x; o[5]=(f16)v1.y; o[6]=(f16)v1.z; o[7]=(f16)v1.w;
    *(f16x8*)(kf + i8) = o;
}

__global__ __launch_bounds__(256) void pack_pw(const float* __restrict__ w,
                                               f16* __restrict__ wf) {
    const size_t i8 = ((size_t)blockIdx.x * 256 + threadIdx.x) << 3;
    const float* src = w + i8;
    float4 v0 = *(const float4*)src;
    float4 v1 = *(const float4*)(src + 4);
    f16x8 o;
    o[0]=(f16)v0.x; o[1]=(f16)v0.y; o[2]=(f16)v0.z; o[3]=(f16)v0.w;
    o[4]=(f16)v1.x; o[5]=(f16)v1.y; o[6]=(f16)v1.z; o[7]=(f16)v1.w;
    *(f16x8*)(wf + i8) = o;
}

__global__ __launch_bounds__(256) void pack_vt(const float* __restrict__ qkv,
                                               f16* __restrict__ vt) {
    const int z = blockIdx.x, b = z >> 3, h = z & 7;
    const float* V = qkv + (size_t)b * N_ * QKVLD + 2 * C_ + h * DH_;
    f16* O = vt + (size_t)z * DH_ * N_;
    __shared__ __align__(16) f16 T[64][72];
    const int t = threadIdx.x;
    for (int m0 = 0; m0 < N_; m0 += 64) {
#pragma unroll
        for (int it = 0; it < 4; ++it) {
            const int m = (t >> 4) + it * 16, d = (t & 15) * 4;
            float4 v = *(const float4*)(V + (size_t)(m0 + m) * QKVLD + d);
            T[d + 0][m] = (f16)v.x; T[d + 1][m] = (f16)v.y;
            T[d + 2][m] = (f16)v.z; T[d + 3][m] = (f16)v.w;
        }
        __syncthreads();
#pragma unroll
        for (int it = 0; it < 2; ++it) {
            const int d = (t >> 3) + it * 32, m = (t & 7) << 3;
            *(f16x8*)(O + (size_t)d * N_ + m0 + m) = *(const f16x8*)&T[d][m];
        }
        __syncthreads();
    }
}

// ---------------------------------------------------------------------------
// Fused premix+softmax(2-pass)+postmix+attn-write+PV+proj.
// Block = 512 threads (8 waves), q-tile 16 rows. Grid = 512 (b = bid&7 so each
// XCD keeps one batch's K/V in its L2). Per 128-key slab: wave w owns m-group
// w*16 (QK^T/premix/softmax) and head g=w (PV).
// ---------------------------------------------------------------------------
__global__ __launch_bounds__(512, 4) void fused_attn(
    const float* __restrict__ qkv,
    const f16*  __restrict__ kf,
    const f16*  __restrict__ vt,
    const f16*  __restrict__ pwf,
    const float* __restrict__ mask,
    const float* __restrict__ pl_w, const float* __restrict__ pl_b,
    const float* __restrict__ pw_w, const float* __restrict__ pw_b,
    const float* __restrict__ proj_b,
    float* __restrict__ attn,
    float* __restrict__ out)
{
    __shared__ __align__(16) f16 Qs[16][520];     // Q f16 scaled; later o1 tile
    __shared__ __align__(16) f16 Ps[8][16][136];  // attn2 f16 [g][q][m128]
    __shared__ float Stat[8][8][2][16];           // [wave][g][M/S][q]

    const int flat = blockIdx.x;
    const int b = flat & 7, qt = flat >> 3;
    const int q0 = qt * 16;
    const int tid = threadIdx.x;
    const int w = tid >> 6, l = tid & 63;
    const int lc = l & 15, lr4 = l >> 4;

    // stage Q tile (16 x 512) -> f16 with SCALE folded (exact pow2)
    {
        const int qrow = tid >> 5, c0 = (tid & 31) << 4;
        const float* src = qkv + (size_t)(b * N_ + q0 + qrow) * QKVLD + c0;
#pragma unroll
        for (int c = 0; c < 16; c += 4) {
            float4 v = *(const float4*)(src + c);
            f16x4 o;
            o[0]=(f16)(v.x*SCALE_); o[1]=(f16)(v.y*SCALE_);
            o[2]=(f16)(v.z*SCALE_); o[3]=(f16)(v.w*SCALE_);
            *(f16x4*)&Qs[qrow][c0 + c] = o;
        }
    }
    __syncthreads();

    const f16* kfb = kf + (size_t)b * N_ * C_;
    const float* maskb = mask + b * N_;

    float mx[8], sm[8];
#pragma unroll
    for (int g = 0; g < 8; ++g) { mx[g] = -3.0e38f; sm[g] = 0.f; }

    // -------- phase 1: online max/sum of premixed logits --------
    for (int mt = 0; mt < N_; mt += 128) {
        const int mb = mt + (w << 4);
        float4 mk4 = *(const float4*)(maskb + mb + (lr4 << 2));
        float mkv[4] = {(1.f-mk4.x)*NEG_, (1.f-mk4.y)*NEG_,
                        (1.f-mk4.z)*NEG_, (1.f-mk4.w)*NEG_};
        float a[8][4];
#pragma unroll
        for (int g = 0; g < 8; ++g) {
            const float bb = pl_b[g];
#pragma unroll
            for (int r = 0; r < 4; ++r) a[g][r] = bb + mkv[r];
        }
#pragma unroll
        for (int h = 0; h < 8; ++h) {
            f32x4 s = (f32x4){0.f, 0.f, 0.f, 0.f};
#pragma unroll
            for (int kk = 0; kk < 2; ++kk) {
                const int c = (h << 6) + (kk << 5) + (lr4 << 3);
                f16x8 af = *(const f16x8*)(kfb + (size_t)(mb + lc) * C_ + c);
                f16x8 bf = *(const f16x8*)&Qs[lc][c];
                s = __builtin_amdgcn_mfma_f32_16x16x32_f16(af, bf, s, 0, 0, 0);
            }
#pragma unroll
            for (int g = 0; g < 8; ++g) {
                const float wv = pl_w[(g << 3) + h];
#pragma unroll
                for (int r = 0; r < 4; ++r) a[g][r] = fmaf(wv, s[r], a[g][r]);
            }
        }
#pragma unroll
        for (int g = 0; g < 8; ++g) {
            float pm = fmaxf(fmaxf(a[g][0], a[g][1]), fmaxf(a[g][2], a[g][3]));
            float nm = fmaxf(mx[g], pm);
            float t  = sm[g] * __expf(mx[g] - nm);
#pragma unroll
            for (int r = 0; r < 4; ++r) t += __expf(a[g][r] - nm);
            sm[g] = t; mx[g] = nm;
        }
    }
    // in-wave combine across lr4 m-subgroups (q = lc invariant under xor 16/32)
#pragma unroll
    for (int g = 0; g < 8; ++g) {
#pragma unroll
        for (int off = 16; off < 64; off <<= 1) {
            float m2 = __shfl_xor(mx[g], off);
            float s2 = __shfl_xor(sm[g], off);
            float nm = fmaxf(mx[g], m2);
            sm[g] = sm[g] * __expf(mx[g] - nm) + s2 * __expf(m2 - nm);
            mx[g] = nm;
        }
    }
    if (l < 16) {
#pragma unroll
        for (int g = 0; g < 8; ++g) {
            Stat[w][g][0][l] = mx[g];
            Stat[w][g][1][l] = sm[g];
        }
    }
    __syncthreads();
    float invs[8];
#pragma unroll
    for (int g = 0; g < 8; ++g) {
        float M = Stat[0][g][0][lc];
#pragma unroll
        for (int wv = 1; wv < 8; ++wv) M = fmaxf(M, Stat[wv][g][0][lc]);
        float S = 0.f;
#pragma unroll
        for (int wv = 0; wv < 8; ++wv)
            S += Stat[wv][g][1][lc] * __expf(Stat[wv][g][0][lc] - M);
        mx[g] = M;
        invs[g] = 1.f / S;
    }

    // -------- phase 2: recompute, normalize, postmix, write attn2, PV --------
    float* attnb = attn + (size_t)(b * H_) * N_ * N_;
    f32x4 O[4];
#pragma unroll
    for (int df = 0; df < 4; ++df) O[df] = (f32x4){0.f, 0.f, 0.f, 0.f};

    for (int mt = 0; mt < N_; mt += 128) {
        const int mb = mt + (w << 4);
        float4 mk4 = *(const float4*)(maskb + mb + (lr4 << 2));
        float mkv[4] = {(1.f-mk4.x)*NEG_, (1.f-mk4.y)*NEG_,
                        (1.f-mk4.z)*NEG_, (1.f-mk4.w)*NEG_};
        float a[8][4];
#pragma unroll
        for (int g = 0; g < 8; ++g) {
            const float bb = pl_b[g];
#pragma unroll
            for (int r = 0; r < 4; ++r) a[g][r] = bb + mkv[r];
        }
#pragma unroll
        for (int h = 0; h < 8; ++h) {
            f32x4 s = (f32x4){0.f, 0.f, 0.f, 0.f};
#pragma unroll
            for (int kk = 0; kk < 2; ++kk) {
                const int c = (h << 6) + (kk << 5) + (lr4 << 3);
                f16x8 af = *(const f16x8*)(kfb + (size_t)(mb + lc) * C_ + c);
                f16x8 bf = *(const f16x8*)&Qs[lc][c];
                s = __builtin_amdgcn_mfma_f32_16x16x32_f16(af, bf, s, 0, 0, 0);
            }
#pragma unroll
            for (int g = 0; g < 8; ++g) {
                const float wv = pl_w[(g << 3) + h];
#pragma unroll
                for (int r = 0; r < 4; ++r) a[g][r] = fmaf(wv, s[r], a[g][r]);
            }
        }
        float p[8][4];
#pragma unroll
        for (int g = 0; g < 8; ++g)
#pragma unroll
            for (int r = 0; r < 4; ++r)
                p[g][r] = __expf(a[g][r] - mx[g]) * invs[g];

        const int qg = q0 + lc;
        const int mg = mb + (lr4 << 2);
#pragma unroll
        for (int gg = 0; gg < 8; ++gg) {
            const float bb = pw_b[gg];
            float o0 = bb, o1 = bb, o2 = bb, o3 = bb;
#pragma unroll
            for (int g = 0; g < 8; ++g) {
                const float wv = pw_w[(gg << 3) + g];
                o0 = fmaf(wv, p[g][0], o0);
                o1 = fmaf(wv, p[g][1], o1);
                o2 = fmaf(wv, p[g][2], o2);
                o3 = fmaf(wv, p[g][3], o3);
            }
            *(float4*)(attnb + ((size_t)gg * N_ + qg) * N_ + mg) =
                make_float4(o0, o1, o2, o3);
            f16x4 ph; ph[0]=(f16)o0; ph[1]=(f16)o1; ph[2]=(f16)o2; ph[3]=(f16)o3;
            *(f16x4*)&Ps[gg][lc][(w << 4) + (lr4 << 2)] = ph;
        }
        __syncthreads();
        // PV: wave w handles head g=w over the 128-key slab
        {
            const f16* vg = vt + (size_t)(b * H_ + w) * DH_ * N_ + mt;
#pragma unroll
            for (int kk = 0; kk < 4; ++kk) {
                f16x8 bf = *(const f16x8*)&Ps[w][lc][(kk << 5) + (lr4 << 3)];
#pragma unroll
                for (int df = 0; df < 4; ++df) {
                    f16x8 af = *(const f16x8*)(vg + (size_t)((df << 4) + lc) * N_ + (kk << 5) + (lr4 << 3));
                    O[df] = __builtin_amdgcn_mfma_f32_16x16x32_f16(af, bf, O[df], 0, 0, 0);
                }
            }
        }
        __syncthreads();
    }

    // -------- epilogue: o1 -> Qs (f16), fused proj --------
#pragma unroll
    for (int df = 0; df < 4; ++df) {
        f16x4 ph;
        ph[0]=(f16)O[df][0]; ph[1]=(f16)O[df][1];
        ph[2]=(f16)O[df][2]; ph[3]=(f16)O[df][3];
        *(f16x4*)&Qs[lc][(w << 6) + (df << 4) + (lr4 << 2)] = ph;
    }
    __syncthreads();

    {
        f32x4 acc[4];
#pragma unroll
        for (int cof = 0; cof < 4; ++cof) acc[cof] = (f32x4){0.f, 0.f, 0.f, 0.f};
        for (int ci = 0; ci < C_; ci += 32) {
            f16x8 bf = *(const f16x8*)&Qs[lc][ci + (lr4 << 3)];
#pragma unroll
            for (int cof = 0; cof < 4; ++cof) {
                f16x8 af = *(const f16x8*)(pwf + (size_t)((w << 6) + (cof << 4) + lc) * C_ + ci + (lr4 << 3));
                acc[cof] = __builtin_amdgcn_mfma_f32_16x16x32_f16(af, bf, acc[cof], 0, 0, 0);
            }
        }
        float* outb = out + (size_t)(b * N_ + q0) * C_;
#pragma unroll
        for (int cof = 0; cof < 4; ++cof) {
            const int co = (w << 6) + (cof << 4) + (lr4 << 2);
            float4 b4 = *(const float4*)(proj_b + co);
            float4 r;
            r.x = acc[cof][0] + b4.x;
            r.y = acc[cof][1] + b4.y;
            r.z = acc[cof][2] + b4.z;
            r.w = acc[cof][3] + b4.w;
            *(float4*)(outb + (size_t)lc * C_ + co) = r;
        }
    }
}

extern "C" void kernel_launch(void* const* d_in, const int* in_sizes, int n_in,
                              void* d_out, int out_size, void* d_ws, size_t ws_size,
                              hipStream_t stream)
{
    const float* x      = (const float*)d_in[0];
    const float* mask   = (const float*)d_in[1];
    const float* qkv_w  = (const float*)d_in[2];
    const float* qkv_b  = (const float*)d_in[3];
    const float* proj_w = (const float*)d_in[4];
    const float* proj_b = (const float*)d_in[5];
    const float* pl_w   = (const float*)d_in[6];
    const float* pl_b   = (const float*)d_in[7];
    const float* pw_w   = (const float*)d_in[8];
    const float* pw_b   = (const float*)d_in[9];

    float* out  = (float*)d_out;                        // [B,N,C]
    float* attn = out + (size_t)B_ * N_ * C_;           // [B,H,N,N]
    float* qkvb = (float*)d_ws;                         // 50.3 MB
    f16*   kf   = (f16*)(qkvb + (size_t)B_ * N_ * 3 * C_);  // 8.4 MB
    f16*   vt   = kf + (size_t)B_ * N_ * C_;                // 8.4 MB
    f16*   pwf  = vt + (size_t)B_ * N_ * C_;                // 0.5 MB
    (void)in_sizes; (void)n_in; (void)out_size; (void)ws_size;

    // 1) qkv = x @ qkv_w^T + qkv_b
    k_qkv<<<dim3(QKVLD / 128, B_ * N_ / 128), 256, 0, stream>>>(x, qkv_w, qkv_b, qkvb);

    // 2) packs
    pack_kf<<<dim3(2048), 256, 0, stream>>>(qkvb, kf);
    pack_vt<<<dim3(B_ * H_), 256, 0, stream>>>(qkvb, vt);
    pack_pw<<<dim3(128), 256, 0, stream>>>(proj_w, pwf);

    // 3) fused premix+softmax+postmix+attn-write+PV+proj
    fused_attn<<<dim3(512), 512, 0, stream>>>(
        qkvb, kf, vt, pwf, mask, pl_w, pl_b, pw_w, pw_b, proj_b, attn, out);
}